// Round 1
// 1170.202 us; speedup vs baseline: 1.3701x; 1.3701x over previous
//
#include <hip/hip_runtime.h>
#include <hip/hip_bf16.h>

#define LSEQ 384
#define BATCH 32
#define BIGV 1e30f
#define TB_STK 448
#define NN ((size_t)LSEQ * LSEQ)
#define BT 32          // tile size
#define NT 12          // tiles per side
#define PIT 33         // LDS pitch

__device__ __forceinline__ int detect_mmode_wave(const unsigned char* m0, int lane) {
    unsigned char v = m0[lane & 63];
    unsigned long long big = __ballot(v >= 2);
    unsigned long long off = __ballot((((lane & 63) & 3) != 0) && (v != 0));
    return big ? 2 : (off ? 1 : 0);
}
__device__ __forceinline__ bool mask_read(const void* mask, size_t idx, int mmode) {
    if (mmode == 0) return ((const unsigned int*)mask)[idx] != 0;
    if (mmode == 1) return ((const unsigned char*)mask)[idx] != 0;
    return ((const unsigned short*)mask)[idx] != 0;
}
__device__ __forceinline__ void choice_write(void* mask, size_t idx, int c, int mmode) {
    if (mmode == 0) ((unsigned int*)mask)[idx] = (unsigned int)c;
    else if (mmode == 1) ((unsigned char*)mask)[idx] = (unsigned char)c;
    else ((unsigned short*)mask)[idx] = (unsigned short)c;
}

// Unified per-lane edge reduction: min over kk in [lo,hi) of rowp[kk] +
// colp[kk*PIT]. 4 independent accumulator chains (math identical to the
// verified kernel; fminf is exact, order-independent).
__device__ __forceinline__ float edge_min(const float* rowp, const float* colp,
                                          int lo, int hi) {
    float a0 = BIGV, a1 = BIGV, a2 = BIGV, a3 = BIGV;
    int kk = lo;
    for (; kk + 3 < hi; kk += 4) {
        float r0 = rowp[kk], r1 = rowp[kk + 1], r2 = rowp[kk + 2], r3 = rowp[kk + 3];
        const float* cb = colp + kk * PIT;
        float c0 = cb[0], c1 = cb[PIT], c2 = cb[2 * PIT], c3 = cb[3 * PIT];
        a0 = fminf(a0, r0 + c0); a1 = fminf(a1, r1 + c1);
        a2 = fminf(a2, r2 + c2); a3 = fminf(a3, r3 + c3);
    }
    for (; kk < hi; ++kk) a0 = fminf(a0, rowp[kk] + colp[kk * PIT]);
    return fminf(fminf(a0, a1), fminf(a2, a3));
}

// ---------- phase 0: one block (1 wave) per diagonal tile ----------
__global__ __launch_bounds__(64) void diag_kernel(
    float* __restrict__ e_pair, const float* __restrict__ e_unp, void* mask)
{
    __shared__ float dT[BT][PIT];
    __shared__ float epm[BT][PIT];
    __shared__ float s_eunp[BT];

    const int bid = blockIdx.x;
    const int b = bid / NT, t = bid % NT;
    const int lane = threadIdx.x;
    float* dpG = e_pair + (size_t)b * NN;
    const size_t mb = (size_t)b * NN;
    const int mmode = detect_mmode_wave((const unsigned char*)mask, lane);

    if (lane < BT) {
        int i = t * BT + lane;
        float v = e_unp[b * LSEQ + i];
        s_eunp[lane] = v;
        dT[lane][lane] = v;                            // dp[i][i]
        dpG[(size_t)i * LSEQ + i] = v;
        if (i > 0) dpG[(size_t)i * LSEQ + i - 1] = v;  // mirror
    }
    for (int z = lane; z < BT * BT; z += 64) {         // stage masked energies
        int li = z >> 5, lj = z & 31;
        int i = t * BT + li, j = t * BT + lj;
        bool ok = (lj - li > 4) && mask_read(mask, mb + (size_t)i * LSEQ + j, mmode);
        epm[li][lj] = ok ? dpG[(size_t)i * LSEQ + j] : BIGV;
    }
    __syncthreads();

    const int idx = lane >> 1, h = lane & 1;
    for (int sg = 1; sg < BT; ++sg) {
        const int nc = BT - sg;
        const bool act = idx < nc;
        const int li = idx, lj = idx + sg;
        const int i = t * BT + li, j = t * BT + lj;
        int lo = li, hi = lj;
        if (!act || h == 1) { lo = 0; hi = 0; }
        float ev = edge_min(&dT[li][0], &dT[1][lj], lo, hi);
        float e1 = BIGV, opt0 = 0.f, x1 = BIGV, x2 = BIGV;
        if (act) {
            if (h == 0) {
                e1 = ev;                               // includes opt0(kk=li), opt1(kk=lj-1)
                opt0 = dT[li + 1][lj] + s_eunp[li];
            } else {
                x1 = dT[li][lj - 1] + s_eunp[lj];
                float pe = epm[li][lj];
                if (pe < BIGV) x2 = dT[li + 1][lj - 1] + pe;
            }
        }
        float y1 = __shfl_xor(x1, 1), y2 = __shfl_xor(x2, 1);
        if (act && h == 0) {
            float best = fminf(e1, y2);
            int cch = (best == opt0) ? 0 : (best == y1) ? 1
                     : (best == y2 && y2 < BIGV) ? 2 : 3;
            dT[li][lj] = best;
            dpG[(size_t)i * LSEQ + j] = best;
            if (i > 0) dpG[(size_t)j * LSEQ + i - 1] = best;
            choice_write(mask, mb + (size_t)j * LSEQ + i, cch, mmode);
        }
    }
}

// ---------- phase s (1..NT-1): one block (4 waves) per tile (I, I+s).
// Inter-phase dependency = stream-ordered kernel boundary (no barriers).
// Waves 0-3 split far-init over M (stride 4) + merge; wave 0 sweeps alone.
__global__ __launch_bounds__(256) void phase_kernel(
    float* __restrict__ e_pair, const float* __restrict__ e_unp, void* mask, int s)
{
    __shared__ float dTI[BT][PIT], dTJ[BT][PIT];
    __shared__ float cur[BT][PIT], epm[BT][PIT];
    __shared__ float part[4][BT][PIT];
    __shared__ float brow[BT], bcol[BT], s_eI[BT], s_eJ[BT];
    __shared__ float bcorn;

    const int nt = NT - s;
    const int bid = blockIdx.x;
    const int b = bid / nt, I = bid % nt, J = I + s;
    const int tid = threadIdx.x, lane = tid & 63, wv = tid >> 6;
    float* dpG = e_pair + (size_t)b * NN;
    const size_t mb = (size_t)b * NN;
    const int mmode = detect_mmode_wave((const unsigned char*)mask, lane);

    // stage the two diagonal tiles (only upper+diag entries are ever read)
    for (int z = tid; z < BT * BT; z += 256) {
        int li = z >> 5, lj = z & 31;
        dTI[li][lj] = dpG[(size_t)(I * BT + li) * LSEQ + I * BT + lj];
        dTJ[li][lj] = dpG[(size_t)(J * BT + li) * LSEQ + J * BT + lj];
    }
    if (tid < BT) {
        brow[tid] = dpG[(size_t)((I + 1) * BT) * LSEQ + J * BT + tid];
        s_eI[tid] = e_unp[b * LSEQ + I * BT + tid];
    } else if (tid < 2 * BT) {
        int q = tid - BT;
        bcol[q] = dpG[(size_t)(I * BT + q) * LSEQ + J * BT - 1];
        s_eJ[q] = e_unp[b * LSEQ + J * BT + q];
    } else if (tid == 2 * BT) {
        bcorn = (s >= 2) ? dpG[(size_t)((I + 1) * BT) * LSEQ + J * BT - 1] : BIGV;
    }
    for (int z = tid; z < BT * BT; z += 256) {         // stage masked energies
        int li = z >> 5, lj = z & 31;
        int i = I * BT + li, j = J * BT + lj;
        bool ok = (j - i > 4) && mask_read(mask, mb + (size_t)i * LSEQ + j, mmode);
        epm[li][lj] = ok ? dpG[(size_t)i * LSEQ + j] : BIGV;
    }

    // far-init: 4-way split over middle tiles M, exact same term set
    if (s == 1) {
        for (int z = tid; z < BT * PIT; z += 256) ((float*)cur)[z] = BIGV;
    } else {
        const int r0 = (lane >> 3) << 2, c0 = (lane & 7) << 2;
        float r16[16];
        #pragma unroll
        for (int z = 0; z < 16; ++z) r16[z] = BIGV;
        for (int M = I + 1 + wv; M < J; M += 4) {
            #pragma unroll
            for (int kq = 0; kq < 8; ++kq) {
                const int k = M * BT + kq * 4;
                float4 a0 = *(const float4*)&dpG[(size_t)(I * BT + r0 + 0) * LSEQ + k];
                float4 a1 = *(const float4*)&dpG[(size_t)(I * BT + r0 + 1) * LSEQ + k];
                float4 a2 = *(const float4*)&dpG[(size_t)(I * BT + r0 + 2) * LSEQ + k];
                float4 a3 = *(const float4*)&dpG[(size_t)(I * BT + r0 + 3) * LSEQ + k];
                float4 b0 = *(const float4*)&dpG[(size_t)(J * BT + c0 + 0) * LSEQ + k];
                float4 b1 = *(const float4*)&dpG[(size_t)(J * BT + c0 + 1) * LSEQ + k];
                float4 b2 = *(const float4*)&dpG[(size_t)(J * BT + c0 + 2) * LSEQ + k];
                float4 b3 = *(const float4*)&dpG[(size_t)(J * BT + c0 + 3) * LSEQ + k];
                #pragma unroll
                for (int ri = 0; ri < 4; ++ri) {
                    float4 av = ri == 0 ? a0 : ri == 1 ? a1 : ri == 2 ? a2 : a3;
                    #pragma unroll
                    for (int ci = 0; ci < 4; ++ci) {
                        float4 bv = ci == 0 ? b0 : ci == 1 ? b1 : ci == 2 ? b2 : b3;
                        float m = fminf(fminf(av.x + bv.x, av.y + bv.y),
                                        fminf(av.z + bv.z, av.w + bv.w));
                        r16[ri * 4 + ci] = fminf(r16[ri * 4 + ci], m);
                    }
                }
            }
        }
        #pragma unroll
        for (int ri = 0; ri < 4; ++ri)
            #pragma unroll
            for (int ci = 0; ci < 4; ++ci)
                part[wv][r0 + ri][c0 + ci] = r16[ri * 4 + ci];
        __syncthreads();
        for (int z = tid; z < BT * BT; z += 256) {
            int li = z >> 5, lj = z & 31;
            cur[li][lj] = fminf(fminf(part[0][li][lj], part[1][li][lj]),
                                fminf(part[2][li][lj], part[3][li][lj]));
        }
    }
    __syncthreads();
    if (wv != 0) return;   // wave 0 sweeps with an unshared SIMD

    const int idx = lane >> 1, h = lane & 1;
    for (int sg = -(BT - 1); sg <= BT - 1; ++sg) {
        const int asg = sg < 0 ? -sg : sg;
        const int nc = BT - asg;
        const bool act = idx < nc;
        const int li = (sg >= 0) ? idx : idx - sg;
        const int lj = li + sg;
        const int i = I * BT + li, j = J * BT + lj;
        const float* rowp; const float* colp; int lo, hi;
        if (h == 0) { rowp = &dTI[li][0]; colp = &cur[1][lj]; lo = li; hi = BT - 1; }
        else        { rowp = &cur[li][0]; colp = &dTJ[1][lj]; lo = 0;  hi = lj; }
        if (!act) { lo = 0; hi = 0; }
        float ev = edge_min(rowp, colp, lo, hi);
        float e1 = BIGV, opt0 = 0.f, farv = BIGV;
        float x0 = BIGV, x1 = BIGV, x2 = BIGV;
        if (act) {
            if (h == 0) {
                e1 = fminf(ev, dTI[li][BT - 1] + brow[lj]);
                opt0 = ((li + 1 < BT) ? cur[li + 1][lj] : brow[lj]) + s_eI[li];
                farv = cur[li][lj];
            } else {
                x0 = ev;
                x1 = ((lj >= 1) ? cur[li][lj - 1] : bcol[li]) + s_eJ[lj];
                float pe = epm[li][lj];
                if (pe < BIGV) {
                    float inner = (li + 1 < BT)
                        ? ((lj >= 1) ? cur[li + 1][lj - 1] : bcol[li + 1])
                        : ((lj >= 1) ? brow[lj - 1] : bcorn);
                    x2 = inner + pe;
                }
            }
        }
        float y0 = __shfl_xor(x0, 1), y1 = __shfl_xor(x1, 1), y2 = __shfl_xor(x2, 1);
        if (act && h == 0) {
            float best = fminf(fminf(fminf(e1, y0), farv), y2);
            int cch = (best == opt0) ? 0 : (best == y1) ? 1
                     : (best == y2 && y2 < BIGV) ? 2 : 3;
            cur[li][lj] = best;
            dpG[(size_t)i * LSEQ + j] = best;
            if (i > 0) dpG[(size_t)j * LSEQ + i - 1] = best;
            choice_write(mask, mb + (size_t)j * LSEQ + i, cch, mmode);
        }
    }
}

// Traceback: R12-proven control flow, but choices cached in LDS as bytes
// (values are 0..3) so the dependent read chain is ~40cy LDS, not ~400cy L2/L3.
__global__ __launch_bounds__(64) void tb_kernel(
    const float* __restrict__ e_pair, const void* mask, float* __restrict__ out)
{
    const int b = blockIdx.x;
    const int lane = threadIdx.x;
    const float* dp = e_pair + (size_t)b * NN;
    const size_t mb = (size_t)b * NN;
    const int mmode = detect_mmode_wave((const unsigned char*)mask, lane);

    __shared__ __align__(16) unsigned char ch[LSEQ * LSEQ];   // 147456 B
    __shared__ short res[LSEQ];
    __shared__ int st[TB_STK];

    if (mmode == 1) {
        const uint4* src = (const uint4*)((const unsigned char*)mask + mb);
        for (int z = lane; z < (int)(NN / 16); z += 64) ((uint4*)ch)[z] = src[z];
    } else if (mmode == 2) {
        const uint4* src = (const uint4*)((const unsigned char*)mask + mb * 2);
        for (int z = lane; z < (int)(NN / 8); z += 64) {
            uint4 v = src[z];
            unsigned int lo = (v.x & 0xFFu) | (((v.x >> 16) & 0xFFu) << 8)
                            | ((v.y & 0xFFu) << 16) | (((v.y >> 16) & 0xFFu) << 24);
            unsigned int hi = (v.z & 0xFFu) | (((v.z >> 16) & 0xFFu) << 8)
                            | ((v.w & 0xFFu) << 16) | (((v.w >> 16) & 0xFFu) << 24);
            ((unsigned int*)ch)[z * 2] = lo;
            ((unsigned int*)ch)[z * 2 + 1] = hi;
        }
    } else {
        const uint4* src = (const uint4*)((const unsigned char*)mask + mb * 4);
        for (int z = lane; z < (int)(NN / 4); z += 64) {
            uint4 v = src[z];
            ((unsigned int*)ch)[z] = (v.x & 0xFFu) | ((v.y & 0xFFu) << 8)
                                   | ((v.z & 0xFFu) << 16) | ((v.w & 0xFFu) << 24);
        }
    }
    for (int l = lane; l < LSEQ; l += 64) res[l] = -1;
    st[0] = (0 << 16) | (LSEQ - 1);
    __syncthreads();

    int sp = 1;
    for (int iter = 0; iter < 4096 && sp > 0; ++iter) {
        --sp;
        int pk = st[sp];
        int i = pk >> 16, j = pk & 0xFFFF;
        if (i >= j) continue;
        int c = ch[(size_t)j * LSEQ + i];
        if (c == 0) { st[sp] = ((i + 1) << 16) | j; ++sp; }
        else if (c == 1) { st[sp] = (i << 16) | (j - 1); ++sp; }
        else if (c == 2) {
            res[i] = (short)j; res[j] = (short)i;
            if (i + 1 <= j - 1) { st[sp] = ((i + 1) << 16) | (j - 1); ++sp; }
        } else {
            const int d = j - i;
            const float* rowi = dp + (size_t)i * LSEQ;
            const float* mrow = dp + (size_t)j * LSEQ;
            float bv = BIGV; int bt = d;
            for (int t = lane; t < d; t += 64) {
                float cc = rowi[i + t] + mrow[i + t];
                if (cc < bv || (cc == bv && t < bt)) { bv = cc; bt = t; }
            }
            for (int m = 32; m > 0; m >>= 1) {
                float ov = __shfl_xor(bv, m, 64);
                int   ot = __shfl_xor(bt, m, 64);
                if (ov < bv || (ov == bv && ot < bt)) { bv = ov; bt = ot; }
            }
            int k = i + bt;
            if (sp < TB_STK - 2) {
                st[sp] = (i << 16) | k; ++sp;
                st[sp] = ((k + 1) << 16) | j; ++sp;
            }
        }
        __syncthreads();
    }

    for (int l = lane; l < LSEQ; l += 64)
        out[b * LSEQ + l] = (float)res[l];
    if (lane == 0)
        out[BATCH * LSEQ + b] = dp[LSEQ - 1];
}

extern "C" void kernel_launch(void* const* d_in, const int* in_sizes, int n_in,
                              void* d_out, int out_size, void* d_ws, size_t ws_size,
                              hipStream_t stream) {
    float* e_pair = (float*)d_in[0];
    const float* e_unp = (const float*)d_in[1];
    void* mask = d_in[2];
    (void)d_ws; (void)ws_size;

    // Phase dependencies carried by stream order (kernel-boundary
    // acquire/release) instead of intra-block barriers -> tiles spread
    // across the whole chip instead of 32 CUs.
    diag_kernel<<<BATCH * NT, 64, 0, stream>>>(e_pair, e_unp, mask);
    for (int s = 1; s < NT; ++s)
        phase_kernel<<<BATCH * (NT - s), 256, 0, stream>>>(e_pair, e_unp, mask, s);
    tb_kernel<<<BATCH, 64, 0, stream>>>(e_pair, mask, (float*)d_out);
}

// Round 2
// 860.442 us; speedup vs baseline: 1.8633x; 1.3600x over previous
//
#include <hip/hip_runtime.h>
#include <hip/hip_bf16.h>

#define LSEQ 384
#define BATCH 32
#define BIGV 1e30f
#define TB_STK 448
#define NN ((size_t)LSEQ * LSEQ)
#define BT 32          // tile size
#define NT 12          // tiles per side
#define PIT 33         // LDS pitch

__device__ __forceinline__ int detect_mmode_wave(const unsigned char* m0, int lane) {
    unsigned char v = m0[lane & 63];
    unsigned long long big = __ballot(v >= 2);
    unsigned long long off = __ballot((((lane & 63) & 3) != 0) && (v != 0));
    return big ? 2 : (off ? 1 : 0);
}
__device__ __forceinline__ bool mask_read(const void* mask, size_t idx, int mmode) {
    if (mmode == 0) return ((const unsigned int*)mask)[idx] != 0;
    if (mmode == 1) return ((const unsigned char*)mask)[idx] != 0;
    return ((const unsigned short*)mask)[idx] != 0;
}
__device__ __forceinline__ void choice_write(void* mask, size_t idx, int c, int mmode) {
    if (mmode == 0) ((unsigned int*)mask)[idx] = (unsigned int)c;
    else if (mmode == 1) ((unsigned char*)mask)[idx] = (unsigned char)c;
    else ((unsigned short*)mask)[idx] = (unsigned short)c;
}

// Fixed-length branchless edge reduction: min over kk in [0,32) of
// rowp[kk] + colp[kk*PIT]. Out-of-range terms are made >= 1e30 by
// BIGV-prefilled lower triangles / pad rows, so they never win or tie
// (real dp values < 1e4) -> results bitwise identical to the ranged
// version. Fully unrolled: all 64 LDS loads issue back-to-back ->
// throughput-bound instead of latency-bound.
__device__ __forceinline__ float edge_min32(const float* rowp, const float* colp) {
    float a0 = BIGV, a1 = BIGV, a2 = BIGV, a3 = BIGV;
    #pragma unroll
    for (int kk = 0; kk < 32; kk += 4) {
        float r0 = rowp[kk], r1 = rowp[kk + 1], r2 = rowp[kk + 2], r3 = rowp[kk + 3];
        const float* cb = colp + kk * PIT;
        float c0 = cb[0], c1 = cb[PIT], c2 = cb[2 * PIT], c3 = cb[3 * PIT];
        a0 = fminf(a0, r0 + c0); a1 = fminf(a1, r1 + c1);
        a2 = fminf(a2, r2 + c2); a3 = fminf(a3, r3 + c3);
    }
    return fminf(fminf(a0, a1), fminf(a2, a3));
}

// ---------- phase 0: one block (1 wave) per diagonal tile ----------
__global__ __launch_bounds__(64) void diag_kernel(
    float* __restrict__ e_pair, const float* __restrict__ e_unp, void* mask)
{
    __shared__ float dT[BT + 1][PIT];   // BIGV-prefilled; row 32 = pad
    __shared__ float epm[BT][PIT];
    __shared__ float s_eunp[BT];

    const int bid = blockIdx.x;
    const int b = bid / NT, t = bid % NT;
    const int lane = threadIdx.x;
    float* dpG = e_pair + (size_t)b * NN;
    const size_t mb = (size_t)b * NN;
    const int mmode = detect_mmode_wave((const unsigned char*)mask, lane);

    for (int z = lane; z < (BT + 1) * PIT; z += 64) ((float*)dT)[z] = BIGV;
    __syncthreads();
    if (lane < BT) {
        int i = t * BT + lane;
        float v = e_unp[b * LSEQ + i];
        s_eunp[lane] = v;
        dT[lane][lane] = v;                            // dp[i][i]
        dpG[(size_t)i * LSEQ + i] = v;
        if (i > 0) dpG[(size_t)i * LSEQ + i - 1] = v;  // mirror
    }
    for (int z = lane; z < BT * BT; z += 64) {         // stage masked energies
        int li = z >> 5, lj = z & 31;
        int i = t * BT + li, j = t * BT + lj;
        bool ok = (lj - li > 4) && mask_read(mask, mb + (size_t)i * LSEQ + j, mmode);
        epm[li][lj] = ok ? dpG[(size_t)i * LSEQ + j] : BIGV;
    }
    __syncthreads();

    const int idx = lane >> 1, h = lane & 1;
    for (int sg = 1; sg < BT; ++sg) {
        const int nc = BT - sg;
        const bool act = idx < nc;
        const int li = idx, lj = idx + sg;
        const int ljc = lj < BT ? lj : BT - 1;         // clamp for inactive lanes
        const int i = t * BT + li, j = t * BT + lj;
        // h0 edge over real kk in [li, lj); padding terms >= 1e30.
        float ev = edge_min32(&dT[li][0], &dT[1][ljc]);
        float e1 = BIGV, opt0 = 0.f, x1 = BIGV, x2 = BIGV;
        if (act) {
            if (h == 0) {
                e1 = ev;                               // includes opt0(kk=li), opt1(kk=lj-1)
                opt0 = dT[li + 1][lj] + s_eunp[li];
            } else {
                x1 = dT[li][lj - 1] + s_eunp[lj];
                float pe = epm[li][lj];
                if (pe < BIGV) x2 = dT[li + 1][lj - 1] + pe;
            }
        }
        float y1 = __shfl_xor(x1, 1), y2 = __shfl_xor(x2, 1);
        if (act && h == 0) {
            float best = fminf(e1, y2);
            int cch = (best == opt0) ? 0 : (best == y1) ? 1
                     : (best == y2 && y2 < BIGV) ? 2 : 3;
            dT[li][lj] = best;
            dpG[(size_t)i * LSEQ + j] = best;
            if (i > 0) dpG[(size_t)j * LSEQ + i - 1] = best;
            choice_write(mask, mb + (size_t)j * LSEQ + i, cch, mmode);
        }
    }
}

// ---------- phase s (1..NT-1): one block (4 waves) per tile (I, I+s).
// Inter-phase dependency = stream-ordered kernel boundary (no barriers).
// Waves 0-3 split far-init over M (stride 4) + merge; wave 0 sweeps alone.
__global__ __launch_bounds__(256) void phase_kernel(
    float* __restrict__ e_pair, const float* __restrict__ e_unp, void* mask, int s)
{
    __shared__ float dTI[BT + 1][PIT], dTJ[BT + 1][PIT];  // strict lower + pad = BIGV
    __shared__ float cur[BT + 1][PIT];                    // row 32 = pad BIGV
    __shared__ float epm[BT][PIT];
    __shared__ float part[4][BT][PIT];
    __shared__ float brow[BT], bcol[BT], s_eI[BT], s_eJ[BT];
    __shared__ float bcorn;

    const int nt = NT - s;
    const int bid = blockIdx.x;
    const int b = bid / nt, I = bid % nt, J = I + s;
    const int tid = threadIdx.x, lane = tid & 63, wv = tid >> 6;
    float* dpG = e_pair + (size_t)b * NN;
    const size_t mb = (size_t)b * NN;
    const int mmode = detect_mmode_wave((const unsigned char*)mask, lane);

    // stage the two diagonal tiles; strict lower triangle -> BIGV
    for (int z = tid; z < BT * BT; z += 256) {
        int li = z >> 5, lj = z & 31;
        dTI[li][lj] = (lj >= li) ? dpG[(size_t)(I * BT + li) * LSEQ + I * BT + lj] : BIGV;
        dTJ[li][lj] = (lj >= li) ? dpG[(size_t)(J * BT + li) * LSEQ + J * BT + lj] : BIGV;
    }
    for (int z = tid; z < PIT; z += 256) {             // pad rows
        dTI[BT][z] = BIGV; dTJ[BT][z] = BIGV; cur[BT][z] = BIGV;
    }
    if (tid < BT) {
        brow[tid] = dpG[(size_t)((I + 1) * BT) * LSEQ + J * BT + tid];
        s_eI[tid] = e_unp[b * LSEQ + I * BT + tid];
    } else if (tid < 2 * BT) {
        int q = tid - BT;
        bcol[q] = dpG[(size_t)(I * BT + q) * LSEQ + J * BT - 1];
        s_eJ[q] = e_unp[b * LSEQ + J * BT + q];
    } else if (tid == 2 * BT) {
        bcorn = (s >= 2) ? dpG[(size_t)((I + 1) * BT) * LSEQ + J * BT - 1] : BIGV;
    }
    for (int z = tid; z < BT * BT; z += 256) {         // stage masked energies
        int li = z >> 5, lj = z & 31;
        int i = I * BT + li, j = J * BT + lj;
        bool ok = (j - i > 4) && mask_read(mask, mb + (size_t)i * LSEQ + j, mmode);
        epm[li][lj] = ok ? dpG[(size_t)i * LSEQ + j] : BIGV;
    }

    // far-init: 4-way split over middle tiles M, exact same term set
    if (s == 1) {
        for (int z = tid; z < BT * PIT; z += 256) ((float*)cur)[z] = BIGV;
    } else {
        const int r0 = (lane >> 3) << 2, c0 = (lane & 7) << 2;
        float r16[16];
        #pragma unroll
        for (int z = 0; z < 16; ++z) r16[z] = BIGV;
        for (int M = I + 1 + wv; M < J; M += 4) {
            #pragma unroll
            for (int kq = 0; kq < 8; ++kq) {
                const int k = M * BT + kq * 4;
                float4 a0 = *(const float4*)&dpG[(size_t)(I * BT + r0 + 0) * LSEQ + k];
                float4 a1 = *(const float4*)&dpG[(size_t)(I * BT + r0 + 1) * LSEQ + k];
                float4 a2 = *(const float4*)&dpG[(size_t)(I * BT + r0 + 2) * LSEQ + k];
                float4 a3 = *(const float4*)&dpG[(size_t)(I * BT + r0 + 3) * LSEQ + k];
                float4 b0 = *(const float4*)&dpG[(size_t)(J * BT + c0 + 0) * LSEQ + k];
                float4 b1 = *(const float4*)&dpG[(size_t)(J * BT + c0 + 1) * LSEQ + k];
                float4 b2 = *(const float4*)&dpG[(size_t)(J * BT + c0 + 2) * LSEQ + k];
                float4 b3 = *(const float4*)&dpG[(size_t)(J * BT + c0 + 3) * LSEQ + k];
                #pragma unroll
                for (int ri = 0; ri < 4; ++ri) {
                    float4 av = ri == 0 ? a0 : ri == 1 ? a1 : ri == 2 ? a2 : a3;
                    #pragma unroll
                    for (int ci = 0; ci < 4; ++ci) {
                        float4 bv = ci == 0 ? b0 : ci == 1 ? b1 : ci == 2 ? b2 : b3;
                        float m = fminf(fminf(av.x + bv.x, av.y + bv.y),
                                        fminf(av.z + bv.z, av.w + bv.w));
                        r16[ri * 4 + ci] = fminf(r16[ri * 4 + ci], m);
                    }
                }
            }
        }
        #pragma unroll
        for (int ri = 0; ri < 4; ++ri)
            #pragma unroll
            for (int ci = 0; ci < 4; ++ci)
                part[wv][r0 + ri][c0 + ci] = r16[ri * 4 + ci];
        __syncthreads();
        for (int z = tid; z < BT * BT; z += 256) {
            int li = z >> 5, lj = z & 31;
            cur[li][lj] = fminf(fminf(part[0][li][lj], part[1][li][lj]),
                                fminf(part[2][li][lj], part[3][li][lj]));
        }
    }
    __syncthreads();
    if (wv != 0) return;   // wave 0 sweeps with an unshared SIMD

    const int idx = lane >> 1, h = lane & 1;
    for (int sg = -(BT - 1); sg <= BT - 1; ++sg) {
        const int asg = sg < 0 ? -sg : sg;
        const int nc = BT - asg;
        const bool act = idx < nc;
        const int li = (sg >= 0) ? idx : idx - sg;
        const int lj = li + sg;
        const int lic = li < BT ? li : BT - 1;         // clamp for inactive lanes
        const int ljc = (lj < BT ? (lj >= 0 ? lj : 0) : BT - 1);
        const int i = I * BT + li, j = J * BT + lj;
        // h0: real kk in [li,31): dTI[li][kk] + cur[kk+1][lj]
        // h1: real kk in [0,lj):  cur[li][kk] + dTJ[kk+1][lj]
        const float* rowp = (h == 0) ? &dTI[lic][0] : &cur[lic][0];
        const float* colp = (h == 0) ? &cur[1][ljc] : &dTJ[1][ljc];
        float ev = edge_min32(rowp, colp);
        float e1 = BIGV, opt0 = 0.f, farv = BIGV;
        float x0 = BIGV, x1 = BIGV, x2 = BIGV;
        if (act) {
            if (h == 0) {
                e1 = fminf(ev, dTI[li][BT - 1] + brow[lj]);
                opt0 = ((li + 1 < BT) ? cur[li + 1][lj] : brow[lj]) + s_eI[li];
                farv = cur[li][lj];
            } else {
                x0 = ev;
                x1 = ((lj >= 1) ? cur[li][lj - 1] : bcol[li]) + s_eJ[lj];
                float pe = epm[li][lj];
                if (pe < BIGV) {
                    float inner = (li + 1 < BT)
                        ? ((lj >= 1) ? cur[li + 1][lj - 1] : bcol[li + 1])
                        : ((lj >= 1) ? brow[lj - 1] : bcorn);
                    x2 = inner + pe;
                }
            }
        }
        float y0 = __shfl_xor(x0, 1), y1 = __shfl_xor(x1, 1), y2 = __shfl_xor(x2, 1);
        if (act && h == 0) {
            float best = fminf(fminf(fminf(e1, y0), farv), y2);
            int cch = (best == opt0) ? 0 : (best == y1) ? 1
                     : (best == y2 && y2 < BIGV) ? 2 : 3;
            cur[li][lj] = best;
            dpG[(size_t)i * LSEQ + j] = best;
            if (i > 0) dpG[(size_t)j * LSEQ + i - 1] = best;
            choice_write(mask, mb + (size_t)j * LSEQ + i, cch, mmode);
        }
    }
}

// Traceback: single wave, no per-iteration barrier (every lane reads only
// values it wrote itself: st/res writes are all-lane same-value; cross-lane
// data moves only through register shfl). Current interval cached in regs;
// bifurcation pushes only the second child.
__global__ __launch_bounds__(64) void tb_kernel(
    const float* __restrict__ e_pair, const void* mask, float* __restrict__ out)
{
    const int b = blockIdx.x;
    const int lane = threadIdx.x;
    const float* dp = e_pair + (size_t)b * NN;
    const size_t mb = (size_t)b * NN;
    const int mmode = detect_mmode_wave((const unsigned char*)mask, lane);

    __shared__ __align__(16) unsigned char ch[LSEQ * LSEQ];   // 147456 B
    __shared__ short res[LSEQ];
    __shared__ int st[TB_STK];

    if (mmode == 1) {
        const uint4* src = (const uint4*)((const unsigned char*)mask + mb);
        for (int z = lane; z < (int)(NN / 16); z += 64) ((uint4*)ch)[z] = src[z];
    } else if (mmode == 2) {
        const uint4* src = (const uint4*)((const unsigned char*)mask + mb * 2);
        for (int z = lane; z < (int)(NN / 8); z += 64) {
            uint4 v = src[z];
            unsigned int lo = (v.x & 0xFFu) | (((v.x >> 16) & 0xFFu) << 8)
                            | ((v.y & 0xFFu) << 16) | (((v.y >> 16) & 0xFFu) << 24);
            unsigned int hi = (v.z & 0xFFu) | (((v.z >> 16) & 0xFFu) << 8)
                            | ((v.w & 0xFFu) << 16) | (((v.w >> 16) & 0xFFu) << 24);
            ((unsigned int*)ch)[z * 2] = lo;
            ((unsigned int*)ch)[z * 2 + 1] = hi;
        }
    } else {
        const uint4* src = (const uint4*)((const unsigned char*)mask + mb * 4);
        for (int z = lane; z < (int)(NN / 4); z += 64) {
            uint4 v = src[z];
            ((unsigned int*)ch)[z] = (v.x & 0xFFu) | ((v.y & 0xFFu) << 8)
                                   | ((v.z & 0xFFu) << 16) | ((v.w & 0xFFu) << 24);
        }
    }
    for (int l = lane; l < LSEQ; l += 64) res[l] = -1;
    __syncthreads();

    int sp = 0;
    int ci = 0, cj = LSEQ - 1;
    int have = 1;
    for (int iter = 0; iter < 8192; ++iter) {
        if (!have) {
            if (sp == 0) break;
            --sp;
            int pk = st[sp];
            ci = pk >> 16; cj = pk & 0xFFFF;
        }
        have = 0;
        if (ci >= cj) continue;
        int c = ch[(size_t)cj * LSEQ + ci];
        if (c == 0) { ++ci; have = 1; }
        else if (c == 1) { --cj; have = 1; }
        else if (c == 2) {
            res[ci] = (short)cj; res[cj] = (short)ci;
            if (ci + 1 <= cj - 1) { ++ci; --cj; have = 1; }
        } else {
            const int d = cj - ci;
            const float* rowi = dp + (size_t)ci * LSEQ;
            const float* mrow = dp + (size_t)cj * LSEQ;
            float bv = BIGV; int bt = d;
            for (int t = lane; t < d; t += 64) {
                float cc = rowi[ci + t] + mrow[ci + t];
                if (cc < bv || (cc == bv && t < bt)) { bv = cc; bt = t; }
            }
            for (int m = 32; m > 0; m >>= 1) {
                float ov = __shfl_xor(bv, m, 64);
                int   ot = __shfl_xor(bt, m, 64);
                if (ov < bv || (ov == bv && ot < bt)) { bv = ov; bt = ot; }
            }
            int k = ci + bt;
            if (sp < TB_STK - 1) { st[sp] = ((k + 1) << 16) | cj; ++sp; }
            cj = k; have = 1;   // process (ci, k) next
        }
    }

    for (int l = lane; l < LSEQ; l += 64)
        out[b * LSEQ + l] = (float)res[l];
    if (lane == 0)
        out[BATCH * LSEQ + b] = dp[LSEQ - 1];
}

extern "C" void kernel_launch(void* const* d_in, const int* in_sizes, int n_in,
                              void* d_out, int out_size, void* d_ws, size_t ws_size,
                              hipStream_t stream) {
    float* e_pair = (float*)d_in[0];
    const float* e_unp = (const float*)d_in[1];
    void* mask = d_in[2];
    (void)d_ws; (void)ws_size;

    diag_kernel<<<BATCH * NT, 64, 0, stream>>>(e_pair, e_unp, mask);
    for (int s = 1; s < NT; ++s)
        phase_kernel<<<BATCH * (NT - s), 256, 0, stream>>>(e_pair, e_unp, mask, s);
    tb_kernel<<<BATCH, 64, 0, stream>>>(e_pair, mask, (float*)d_out);
}